// Round 12
// baseline (537.584 us; speedup 1.0000x reference)
//
#include <hip/hip_runtime.h>

typedef __attribute__((ext_vector_type(8))) short bf16x8;
typedef __attribute__((ext_vector_type(4))) float f32x4;
typedef __attribute__((ext_vector_type(4))) unsigned int u32x4;

#define DEVINL __device__ __forceinline__

DEVINL unsigned short f2bf(float f){
  unsigned int u = __float_as_uint(f);
  unsigned int r = (u + 0x7FFFu + ((u >> 16) & 1u)) >> 16;
  return (unsigned short)r;
}
DEVINL float bf2f(unsigned short h){ return __uint_as_float(((unsigned int)h) << 16); }
DEVINL unsigned int fkey(float f){
  unsigned int u = __float_as_uint(f);
  return (u & 0x80000000u) ? ~u : (u | 0x80000000u);
}
DEVINL float fkeyinv(unsigned int k){
  unsigned int u = (k & 0x80000000u) ? (k & 0x7FFFFFFFu) : ~k;
  return __uint_as_float(u);
}
DEVINL unsigned int cvtpk(float lo, float hi){
  unsigned int r;
  asm("v_cvt_pk_bf16_f32 %0, %1, %2" : "=v"(r) : "v"(lo), "v"(hi));
  return r;
}
// async global->LDS 16B: LDS dest = wave-uniform base + lane*16
DEVINL void gload16(void* lds, const void* g){
  __builtin_amdgcn_global_load_lds((const __attribute__((address_space(1))) void*)g,
                                   (__attribute__((address_space(3))) void*)lds, 16, 0, 0);
}

// ---------------- prep (routed, single launch): x -> xh/xl, Wq|Wk|Wv -> whi/wlo --------------
__global__ void prep_all_kernel(const float* __restrict__ x,
                                const float* __restrict__ Wq, const float* __restrict__ Wk,
                                const float* __restrict__ Wv,
                                unsigned short* __restrict__ xh, unsigned short* __restrict__ xl,
                                unsigned short* __restrict__ whi, unsigned short* __restrict__ wlo){
  const int NX = 4194304, NW = 1048576;
  int i = blockIdx.x * 256 + threadIdx.x;
  if (i < NX){
    float f = x[i];
    unsigned short h = f2bf(f);
    xh[i] = h; xl[i] = f2bf(f - bf2f(h));
  } else {
    int j = i - NX;                       // 0 .. 3*NW-1
    const float* W = (j < NW) ? Wq : (j < 2*NW) ? Wk : Wv;
    int o = (j < NW) ? j : (j < 2*NW) ? (j - NW) : (j - 2*NW);
    float f = W[o];
    unsigned short h = f2bf(f);
    whi[j] = h; wlo[j] = f2bf(f - bf2f(h));
  }
}

// ---------------- prep: f32 -> bf16 hi + lo residual (Wo) ----------------
__global__ void prep_split_kernel(const float* __restrict__ src,
                                  unsigned short* __restrict__ hi,
                                  unsigned short* __restrict__ lo, int n){
  int i = blockIdx.x * 256 + threadIdx.x;
  if (i >= n) return;
  float f = src[i];
  unsigned short h = f2bf(f);
  hi[i] = h;
  if (lo) lo[i] = f2bf(f - bf2f(h));
}

// ---------------- GEMM v2: global_load_lds staging, linear LDS, 128x128 tile ----------------
template<bool SPLIT, int EPI>
__global__ __launch_bounds__(256) void gemm_kernel(
    const unsigned short* __restrict__ Ah, const unsigned short* __restrict__ Al,
    const unsigned short* __restrict__ Bh, const unsigned short* __restrict__ Bl,
    const float* __restrict__ bias0, const float* __restrict__ bias1, const float* __restrict__ bias2,
    unsigned short* __restrict__ qh, unsigned short* __restrict__ ql,
    unsigned short* __restrict__ kh, unsigned short* __restrict__ kl,
    unsigned short* __restrict__ vT, float* __restrict__ outf)
{
  const int K = 1024;
  __shared__ __align__(16) unsigned short sAh[128*32];
  __shared__ __align__(16) unsigned short sBh[128*32];
  __shared__ __align__(16) unsigned short sAl[SPLIT ? 128*32 : 8];
  __shared__ __align__(16) unsigned short sBl[SPLIT ? 128*32 : 8];

  const int tid = threadIdx.x;
  const int lane = tid & 63;
  const int w = tid >> 6;
  const int wr = w >> 1, wc = w & 1;
  const int l16 = lane & 15, lg = lane >> 4;
  const int bm = blockIdx.x, bn = blockIdx.y;

  const int srow = (lane >> 2);
  const int scol = (lane & 3) * 8;
  const int r0 = w * 32;

  f32x4 acc[4][4];
  #pragma unroll
  for (int i = 0; i < 4; i++)
    #pragma unroll
    for (int j = 0; j < 4; j++)
      acc[i][j] = (f32x4){0.f,0.f,0.f,0.f};

  for (int kt = 0; kt < K/32; ++kt){
    __syncthreads();
    #pragma unroll
    for (int cc = 0; cc < 2; cc++){
      const int rr = r0 + cc*16 + srow;
      const int lb = (r0 + cc*16) * 32;
      gload16(&sAh[lb], &Ah[(size_t)(bm*128 + rr)*K + kt*32 + scol]);
      gload16(&sBh[lb], &Bh[(size_t)(bn*128 + rr)*K + kt*32 + scol]);
      if constexpr (SPLIT){
        gload16(&sAl[lb], &Al[(size_t)(bm*128 + rr)*K + kt*32 + scol]);
        gload16(&sBl[lb], &Bl[(size_t)(bn*128 + rr)*K + kt*32 + scol]);
      }
    }
    __syncthreads();

    bf16x8 afh[4], afl[4], bfh[4], bfl[4];
    #pragma unroll
    for (int mi = 0; mi < 4; mi++){
      int off = (wr*64 + mi*16 + l16)*32 + lg*8;
      afh[mi] = *(const bf16x8*)&sAh[off];
      if constexpr (SPLIT) afl[mi] = *(const bf16x8*)&sAl[off];
    }
    #pragma unroll
    for (int ni = 0; ni < 4; ni++){
      int off = (wc*64 + ni*16 + l16)*32 + lg*8;
      bfh[ni] = *(const bf16x8*)&sBh[off];
      if constexpr (SPLIT) bfl[ni] = *(const bf16x8*)&sBl[off];
    }
    #pragma unroll
    for (int mi = 0; mi < 4; mi++)
      #pragma unroll
      for (int ni = 0; ni < 4; ni++){
        acc[mi][ni] = __builtin_amdgcn_mfma_f32_16x16x32_bf16(afh[mi], bfh[ni], acc[mi][ni], 0, 0, 0);
        if constexpr (SPLIT){
          acc[mi][ni] = __builtin_amdgcn_mfma_f32_16x16x32_bf16(afh[mi], bfl[ni], acc[mi][ni], 0, 0, 0);
          acc[mi][ni] = __builtin_amdgcn_mfma_f32_16x16x32_bf16(afl[mi], bfh[ni], acc[mi][ni], 0, 0, 0);
        }
      }
  }

  if constexpr (EPI == 0){
    const int wsel = (bn * 128) >> 10;   // 0=Q,1=K,2=V
    const float* bias = (wsel == 0) ? bias0 : (wsel == 1) ? bias1 : bias2;
    #pragma unroll
    for (int mi = 0; mi < 4; mi++)
      #pragma unroll
      for (int ni = 0; ni < 4; ni++)
        #pragma unroll
        for (int i = 0; i < 4; i++){
          int m = bm*128 + wr*64 + mi*16 + lg*4 + i;
          int ng = bn*128 + wc*64 + ni*16 + l16;
          int n = ng & 1023;
          float v = acc[mi][ni][i] + bias[n];
          int b = m >> 11, s = m & 2047;
          int h = n >> 7, dh = n & 127;
          size_t base = (size_t)(b*8 + h)*262144;
          if (wsel == 2){
            size_t off = base + (size_t)(s>>5)*4096 + (dh>>4)*512
                       + (size_t)((((s>>3)&3)*16 + (dh&15))*8 + (s&7));
            vT[off] = f2bf(v);
          } else {
            size_t off = base + (size_t)(s>>4)*2048 + (dh>>5)*512
                       + (size_t)((((dh>>3)&3)*16 + (s&15))*8 + (dh&7));
            unsigned short hv = f2bf(v);
            if (wsel == 0){ qh[off] = hv; ql[off] = f2bf(v - bf2f(hv)); }
            else          { kh[off] = hv; kl[off] = f2bf(v - bf2f(hv)); }
          }
        }
  } else {
    #pragma unroll
    for (int mi = 0; mi < 4; mi++)
      #pragma unroll
      for (int ni = 0; ni < 4; ni++)
        #pragma unroll
        for (int i = 0; i < 4; i++){
          int m = bm*128 + wr*64 + mi*16 + lg*4 + i;
          int n = bn*128 + wc*64 + ni*16 + l16;
          outf[(size_t)m*1024 + n] = acc[mi][ni][i] + bias0[n];
        }
  }
}

// ---------------- fused attention v9: R10 attn + fused distill/gate-mix epilogue --------------
// One block per (b,h,16-row q-block); its 16x128 output tile spans exactly two complete
// 64-col distill blocks -> distill+mix computed in the epilogue, writes mixedh/l directly.
__global__ __launch_bounds__(512, 4) void attn_kernel(
    const unsigned short* __restrict__ qh, const unsigned short* __restrict__ ql,
    const unsigned short* __restrict__ kh, const unsigned short* __restrict__ kl,
    const unsigned short* __restrict__ vT,
    const float* __restrict__ Wd, const float* __restrict__ bd, const float* __restrict__ gate,
    unsigned short* __restrict__ mixedh, unsigned short* __restrict__ mixedl)
{
  __shared__ __align__(16) float red[8][16][132];
  __shared__ float rpartm[8][16], rpartd[8][16];
  __shared__ unsigned int prefixv[16], kremv[16];
  unsigned int* hist = (unsigned int*)red;

  const int tid = threadIdx.x;
  const int lane = tid & 63;
  const int w = tid >> 6;
  const int l16 = lane & 15, lg = lane >> 4;
  const int swz = (blockIdx.x & 7) * 256 + (blockIdx.x >> 3);
  const int bh = swz >> 7, qb = swz & 127;
  const float scale = 0.08838834764831845f;

  const size_t base = (size_t)bh*262144;

  const size_t qpb = base + (size_t)qb*2048 + lane*8;
  bf16x8 aqh[4], aql[4];
  #pragma unroll
  for (int kk = 0; kk < 4; kk++){
    aqh[kk] = *(const bf16x8*)&qh[qpb + kk*512];
    aql[kk] = *(const bf16x8*)&ql[qpb + kk*512];
  }

  f32x4 acc[16];
  #pragma unroll
  for (int nt = 0; nt < 16; nt++){
    f32x4 a0 = (f32x4){0.f,0.f,0.f,0.f};
    f32x4 a1 = (f32x4){0.f,0.f,0.f,0.f};
    const size_t kb = base + (size_t)(w*16 + nt)*2048 + lane*8;
    __builtin_amdgcn_s_setprio(1);
    #pragma unroll
    for (int kk = 0; kk < 4; kk++){
      bf16x8 kbh = *(const bf16x8*)&kh[kb + kk*512];
      bf16x8 kbl = *(const bf16x8*)&kl[kb + kk*512];
      a0 = __builtin_amdgcn_mfma_f32_16x16x32_bf16(kbh, aqh[kk], a0, 0, 0, 0);
      a1 = __builtin_amdgcn_mfma_f32_16x16x32_bf16(kbh, aql[kk], a1, 0, 0, 0);
      a1 = __builtin_amdgcn_mfma_f32_16x16x32_bf16(kbl, aqh[kk], a1, 0, 0, 0);
    }
    __builtin_amdgcn_s_setprio(0);
    #pragma unroll
    for (int i = 0; i < 4; i++) acc[nt][i] = (a0[i] + a1[i]) * scale;
  }

  {
    float rm = -3.4e38f;
    #pragma unroll
    for (int nt = 0; nt < 16; nt++)
      #pragma unroll
      for (int i = 0; i < 4; i++) rm = fmaxf(rm, acc[nt][i]);
    rm = fmaxf(rm, __shfl_xor(rm, 16, 64));
    rm = fmaxf(rm, __shfl_xor(rm, 32, 64));
    if (lane < 16) rpartm[w][lane] = rm;
  }
  if (tid < 16){ prefixv[tid] = 0u; kremv[tid] = 204u; }

  #pragma unroll
  for (int nt = 0; nt < 16; nt++)
    #pragma unroll
    for (int i = 0; i < 4; i++)
      acc[nt][i] = __uint_as_float(fkey(acc[nt][i]));

  const int hco = (w >> 1) * (16*257);
  for (int pass = 3; pass >= 0; pass--){
    const int shift = pass*8;
    __syncthreads();
    for (int j = tid; j < 4*16*257; j += 512) hist[j] = 0u;
    __syncthreads();
    const unsigned int pf = prefixv[l16];
    const unsigned int mhi = (pass == 3) ? 0u : (0xFFFFFFFFu << (shift + 8));
    #pragma unroll
    for (int nt = 0; nt < 16; nt++)
      #pragma unroll
      for (int i = 0; i < 4; i++){
        unsigned int u = __float_as_uint(acc[nt][i]);
        if ((u & mhi) == pf)
          atomicAdd(&hist[hco + l16*257 + ((u >> shift) & 255u)], 1u);
      }
    __syncthreads();
    #pragma unroll
    for (int rr = 0; rr < 2; rr++){
      int r = w*2 + rr;
      unsigned int krem = kremv[r];
      unsigned int pfx  = prefixv[r];
      unsigned int cl[4], s4 = 0;
      #pragma unroll
      for (int t = 0; t < 4; t++){
        int idx = r*257 + 255 - 4*lane - t;
        cl[t] = hist[idx] + hist[16*257 + idx] + hist[2*16*257 + idx] + hist[3*16*257 + idx];
        s4 += cl[t];
      }
      unsigned int inc = s4;
      #pragma unroll
      for (int off = 1; off < 64; off <<= 1){
        unsigned int v = __shfl_up((int)inc, off, 64);
        if (lane >= off) inc += v;
      }
      unsigned int cb = inc - s4;
      #pragma unroll
      for (int t = 0; t < 4; t++){
        if (krem > cb && krem <= cb + cl[t]){
          int d = 255 - 4*lane - t;
          prefixv[r] = pfx | ((unsigned int)d << shift);
          kremv[r]   = krem - cb;
        }
        cb += cl[t];
      }
    }
  }
  __syncthreads();

  const unsigned int th = prefixv[l16];
  float rmax = rpartm[0][l16];
  #pragma unroll
  for (int w8 = 1; w8 < 8; w8++) rmax = fmaxf(rmax, rpartm[w8][l16]);
  const int src01 = ((lg & 1) << 5) + l16;
  const int src23 = src01 + 16;
  const size_t vb0 = base + (size_t)(w*8)*4096 + lane*8;
  float dn = 0.f;
  f32x4 pacc[8];
  #pragma unroll
  for (int dt = 0; dt < 8; dt++) pacc[dt] = (f32x4){0.f,0.f,0.f,0.f};
  #pragma unroll
  for (int t = 0; t < 8; t++){
    float p[8];
    #pragma unroll
    for (int j = 0; j < 4; j++){
      unsigned int u = __float_as_uint(acc[2*t][j]);
      p[j] = (u >= th) ? __expf(fkeyinv(u) - rmax) : 0.f;
    }
    #pragma unroll
    for (int j = 0; j < 4; j++){
      unsigned int u = __float_as_uint(acc[2*t+1][j]);
      p[4+j] = (u >= th) ? __expf(fkeyinv(u) - rmax) : 0.f;
    }
    unsigned int d0 = cvtpk(p[0], p[1]), d1 = cvtpk(p[2], p[3]);
    unsigned int d2 = cvtpk(p[4], p[5]), d3 = cvtpk(p[6], p[7]);
    dn += __uint_as_float(d0 << 16) + __uint_as_float(d0 & 0xFFFF0000u)
        + __uint_as_float(d1 << 16) + __uint_as_float(d1 & 0xFFFF0000u)
        + __uint_as_float(d2 << 16) + __uint_as_float(d2 & 0xFFFF0000u)
        + __uint_as_float(d3 << 16) + __uint_as_float(d3 & 0xFFFF0000u);
    unsigned int A0 = (unsigned int)__shfl((int)d0, src01, 64);
    unsigned int A1 = (unsigned int)__shfl((int)d1, src01, 64);
    unsigned int A2 = (unsigned int)__shfl((int)d0, src23, 64);
    unsigned int A3 = (unsigned int)__shfl((int)d1, src23, 64);
    unsigned int B0 = (unsigned int)__shfl((int)d2, src01, 64);
    unsigned int B1 = (unsigned int)__shfl((int)d3, src01, 64);
    unsigned int B2 = (unsigned int)__shfl((int)d2, src23, 64);
    unsigned int B3 = (unsigned int)__shfl((int)d3, src23, 64);
    u32x4 pdv = (lg < 2) ? (u32x4){A0, A1, A2, A3} : (u32x4){B0, B1, B2, B3};
    bf16x8 pa = __builtin_bit_cast(bf16x8, pdv);
    __builtin_amdgcn_s_setprio(1);
    #pragma unroll
    for (int dt = 0; dt < 8; dt++){
      bf16x8 bv = *(const bf16x8*)&vT[vb0 + (size_t)t*4096 + dt*512];
      pacc[dt] = __builtin_amdgcn_mfma_f32_16x16x32_bf16(pa, bv, pacc[dt], 0, 0, 0);
    }
    __builtin_amdgcn_s_setprio(0);
  }
  dn += __shfl_xor(dn, 16, 64);
  dn += __shfl_xor(dn, 32, 64);
  if (lane < 16) rpartd[w][lane] = dn;

  #pragma unroll
  for (int dt = 0; dt < 8; dt++)
    #pragma unroll
    for (int i = 0; i < 4; i++)
      red[w][lg*4 + i][dt*16 + l16] = pacc[dt][i];
  __syncthreads();

  // epilogue: reduce -> o; then fused distill (64-block matvec) + gate mix -> mixedh/l
  {
    const int q  = tid >> 5;            // 0..15
    const int c0 = (tid & 31) * 4;      // 0..124
    f32x4 s0 = (f32x4){0.f,0.f,0.f,0.f};
    #pragma unroll
    for (int w8 = 0; w8 < 8; w8++)
      s0 += *(const f32x4*)&red[w8][q][c0];
    float dnm = 0.f;
    #pragma unroll
    for (int w8 = 0; w8 < 8; w8++) dnm += rpartd[w8][q];
    f32x4 o;
    #pragma unroll
    for (int i = 0; i < 4; i++) o[i] = s0[i] / dnm;
    // stash o row in red[0] (each thread owns its (q,c0) slice exclusively)
    *(f32x4*)&red[0][q][c0] = o;
    __syncthreads();

    const int b = bh >> 3, h = bh & 7;
    const int j64 = c0 & 64;            // 64-block base within the 128-wide tile
    const int ccb = c0 & 63;            // row index into Wd for output i -> ccb+i
    f32x4 y = (f32x4){bd[ccb], bd[ccb+1], bd[ccb+2], bd[ccb+3]};
    #pragma unroll
    for (int m4 = 0; m4 < 16; m4++){
      f32x4 ov = *(const f32x4*)&red[0][q][j64 + m4*4];
      #pragma unroll
      for (int i = 0; i < 4; i++){
        f32x4 wv = *(const f32x4*)&Wd[(size_t)(ccb + i)*64 + m4*4];
        y[i] += ov[0]*wv[0];
        y[i] += ov[1]*wv[1];
        y[i] += ov[2]*wv[2];
        y[i] += ov[3]*wv[3];
      }
    }
    const int col = h*128 + c0;
    const size_t row = (size_t)b*2048 + qb*16 + q;
    #pragma unroll
    for (int i = 0; i < 4; i++){
      float g  = gate[b*1024 + col + i];
      float mv = g*y[i] + (1.f - g)*o[i];
      unsigned short hv = f2bf(mv);
      mixedh[row*1024 + col + i] = hv;
      mixedl[row*1024 + col + i] = f2bf(mv - bf2f(hv));
    }
  }
}

// ---------------- mean over S: 256 blocks of 16-row partial sums ----------------
__global__ void mean_partial_kernel(const float* __restrict__ x, float* __restrict__ partial){
  int b = blockIdx.x >> 7, ch = blockIdx.x & 127;
  int tid = threadIdx.x;
  #pragma unroll
  for (int dc = 0; dc < 4; dc++){
    int d = dc*256 + tid;
    float s = 0.f;
    for (int ss = 0; ss < 16; ss++) s += x[((size_t)b*2048 + ch*16 + ss)*1024 + d];
    partial[((size_t)b*128 + ch)*1024 + d] = s;
  }
}

// ---------------- gate (merged): xmean -> sigmoid dots -> Wgp projection ----------------------
__global__ __launch_bounds__(512) void gate_kernel2(const float* __restrict__ partial,
    const float* __restrict__ Wg, const float* __restrict__ bg,
    const float* __restrict__ Wgp, const float* __restrict__ bgp, float* __restrict__ gate){
  __shared__ float xm[1024];
  __shared__ float gb[64];
  const int b = blockIdx.x;
  const int tid = threadIdx.x, lane = tid & 63, w = tid >> 6;
  for (int d = tid; d < 1024; d += 512){
    float s = 0.f;
    for (int c = 0; c < 128; c++) s += partial[((size_t)b*128 + c)*1024 + d];
    xm[d] = s * (1.f/2048.f);
  }
  __syncthreads();
  for (int jj = 0; jj < 8; jj++){
    const int j = w*8 + jj;
    float s = 0.f;
    #pragma unroll
    for (int c = 0; c < 4; c++){
      f32x4 wv = *(const f32x4*)&Wg[(size_t)j*1024 + lane*16 + c*4];
      s += wv[0]*xm[lane*16 + c*4] + wv[1]*xm[lane*16 + c*4 + 1]
         + wv[2]*xm[lane*16 + c*4 + 2] + wv[3]*xm[lane*16 + c*4 + 3];
    }
    #pragma unroll
    for (int off = 1; off < 64; off <<= 1) s += __shfl_xor(s, off, 64);
    if (lane == 0) gb[j] = 1.f / (1.f + __expf(-(s + bg[j])));
  }
  __syncthreads();
  for (int d = tid; d < 1024; d += 512){
    float s = bgp[d];
    #pragma unroll
    for (int j4 = 0; j4 < 16; j4++){
      f32x4 wv = *(const f32x4*)&Wgp[(size_t)d*64 + j4*4];
      s += wv[0]*gb[j4*4] + wv[1]*gb[j4*4+1] + wv[2]*gb[j4*4+2] + wv[3]*gb[j4*4+3];
    }
    gate[b*1024 + d] = s;
  }
}

// ---------------- launch ----------------
// Workspace layout (total 68 MiB; replay-proven safe):
//   [ 0, 8)  MiB xh (dead after QKV gemm) -> mixedh (written by attn)
//   [ 8,16)  MiB xl (dead after QKV gemm) -> mixedl
//   [16,22)  MiB whi (dead after QKV gemm) } wohi [16,18), wolo [18,20),
//   [22,28)  MiB wlo (dead after QKV gemm) } partial [20,21), gatews [21,+8K)
//   [28,36)  MiB qh (packed)     [36,44) ql (packed)
//   [44,52)  MiB kh (packed)     [52,60) kl (packed)    [60,68) vT (packed)
extern "C" void kernel_launch(void* const* d_in, const int* in_sizes, int n_in,
                              void* d_out, int out_size, void* d_ws, size_t ws_size,
                              hipStream_t stream){
  (void)in_sizes; (void)n_in; (void)out_size; (void)ws_size;
  const float* x   = (const float*)d_in[0];
  const float* Wq  = (const float*)d_in[1];
  const float* bq  = (const float*)d_in[2];
  const float* Wk  = (const float*)d_in[3];
  const float* bk  = (const float*)d_in[4];
  const float* Wv  = (const float*)d_in[5];
  const float* bv  = (const float*)d_in[6];
  const float* Wo  = (const float*)d_in[7];
  const float* bo  = (const float*)d_in[8];
  const float* Wd  = (const float*)d_in[9];
  const float* bd  = (const float*)d_in[10];
  const float* Wg  = (const float*)d_in[11];
  const float* bg  = (const float*)d_in[12];
  const float* Wgp = (const float*)d_in[13];
  const float* bgp = (const float*)d_in[14];
  float* out = (float*)d_out;

  const size_t MiB = 1048576;
  char* ws = (char*)d_ws;
  unsigned short* xh     = (unsigned short*)(ws + 0*MiB);
  unsigned short* xl     = (unsigned short*)(ws + 8*MiB);
  unsigned short* mixedh = (unsigned short*)(ws + 0*MiB);   // aliases xh after QKV
  unsigned short* mixedl = (unsigned short*)(ws + 8*MiB);   // aliases xl after QKV
  unsigned short* whi    = (unsigned short*)(ws + 16*MiB);  // [3072,1024]
  unsigned short* wlo    = (unsigned short*)(ws + 22*MiB);
  unsigned short* wohi   = (unsigned short*)(ws + 16*MiB);  // aliases whi, written after QKV
  unsigned short* wolo   = (unsigned short*)(ws + 18*MiB);
  float*          partial= (float*)(ws + 20*MiB);           // 1 MiB
  float*          gatews = (float*)(ws + 21*MiB);           // 8 KiB
  unsigned short* qh_    = (unsigned short*)(ws + 28*MiB);
  unsigned short* ql_    = (unsigned short*)(ws + 36*MiB);
  unsigned short* kh_    = (unsigned short*)(ws + 44*MiB);
  unsigned short* kl_    = (unsigned short*)(ws + 52*MiB);
  unsigned short* vT_    = (unsigned short*)(ws + 60*MiB);  // ends at 68 MiB

  prep_all_kernel<<<28672, 256, 0, stream>>>(x, Wq, Wk, Wv, xh, xl, whi, wlo);

  gemm_kernel<true, 0><<<dim3(32, 24), 256, 0, stream>>>(
      xh, xl, whi, wlo, bq, bk, bv, qh_, ql_, kh_, kl_, vT_, nullptr);

  prep_split_kernel<<<4096, 256, 0, stream>>>(Wo, wohi, wolo, 1048576);
  mean_partial_kernel<<<256, 256, 0, stream>>>(x, partial);
  gate_kernel2<<<2, 512, 0, stream>>>(partial, Wg, bg, Wgp, bgp, gatews);

  attn_kernel<<<2048, 512, 0, stream>>>(qh_, ql_, kh_, kl_, vT_,
                                        Wd, bd, gatews, mixedh, mixedl);

  gemm_kernel<true, 1><<<dim3(32, 8), 256, 0, stream>>>(
      mixedh, mixedl, wohi, wolo, bo, nullptr, nullptr,
      nullptr, nullptr, nullptr, nullptr, nullptr, out);
}

// Round 13
// 469.913 us; speedup vs baseline: 1.1440x; 1.1440x over previous
//
#include <hip/hip_runtime.h>

typedef __attribute__((ext_vector_type(8))) short bf16x8;
typedef __attribute__((ext_vector_type(4))) float f32x4;
typedef __attribute__((ext_vector_type(4))) unsigned int u32x4;

#define DEVINL __device__ __forceinline__

DEVINL unsigned short f2bf(float f){
  unsigned int u = __float_as_uint(f);
  unsigned int r = (u + 0x7FFFu + ((u >> 16) & 1u)) >> 16;
  return (unsigned short)r;
}
DEVINL float bf2f(unsigned short h){ return __uint_as_float(((unsigned int)h) << 16); }
DEVINL unsigned int fkey(float f){
  unsigned int u = __float_as_uint(f);
  return (u & 0x80000000u) ? ~u : (u | 0x80000000u);
}
DEVINL float fkeyinv(unsigned int k){
  unsigned int u = (k & 0x80000000u) ? (k & 0x7FFFFFFFu) : ~k;
  return __uint_as_float(u);
}
DEVINL unsigned int cvtpk(float lo, float hi){
  unsigned int r;
  asm("v_cvt_pk_bf16_f32 %0, %1, %2" : "=v"(r) : "v"(lo), "v"(hi));
  return r;
}
// async global->LDS 16B: LDS dest = wave-uniform base + lane*16
DEVINL void gload16(void* lds, const void* g){
  __builtin_amdgcn_global_load_lds((const __attribute__((address_space(1))) void*)g,
                                   (__attribute__((address_space(3))) void*)lds, 16, 0, 0);
}

// ---------------- prep (routed, single launch): x -> xh/xl, Wq|Wk|Wv -> whi/wlo --------------
__global__ void prep_all_kernel(const float* __restrict__ x,
                                const float* __restrict__ Wq, const float* __restrict__ Wk,
                                const float* __restrict__ Wv,
                                unsigned short* __restrict__ xh, unsigned short* __restrict__ xl,
                                unsigned short* __restrict__ whi, unsigned short* __restrict__ wlo){
  const int NX = 4194304, NW = 1048576;
  int i = blockIdx.x * 256 + threadIdx.x;
  if (i < NX){
    float f = x[i];
    unsigned short h = f2bf(f);
    xh[i] = h; xl[i] = f2bf(f - bf2f(h));
  } else {
    int j = i - NX;                       // 0 .. 3*NW-1
    const float* W = (j < NW) ? Wq : (j < 2*NW) ? Wk : Wv;
    int o = (j < NW) ? j : (j < 2*NW) ? (j - NW) : (j - 2*NW);
    float f = W[o];
    unsigned short h = f2bf(f);
    whi[j] = h; wlo[j] = f2bf(f - bf2f(h));
  }
}

// ---------------- prep: f32 -> bf16 hi + lo residual (Wo) ----------------
__global__ void prep_split_kernel(const float* __restrict__ src,
                                  unsigned short* __restrict__ hi,
                                  unsigned short* __restrict__ lo, int n){
  int i = blockIdx.x * 256 + threadIdx.x;
  if (i >= n) return;
  float f = src[i];
  unsigned short h = f2bf(f);
  hi[i] = h;
  if (lo) lo[i] = f2bf(f - bf2f(h));
}

// ---------------- GEMM v2: global_load_lds staging, linear LDS, 128x128 tile ----------------
template<bool SPLIT, int EPI>
__global__ __launch_bounds__(256) void gemm_kernel(
    const unsigned short* __restrict__ Ah, const unsigned short* __restrict__ Al,
    const unsigned short* __restrict__ Bh, const unsigned short* __restrict__ Bl,
    const float* __restrict__ bias0, const float* __restrict__ bias1, const float* __restrict__ bias2,
    unsigned short* __restrict__ qh, unsigned short* __restrict__ ql,
    unsigned short* __restrict__ kh, unsigned short* __restrict__ kl,
    unsigned short* __restrict__ vT, float* __restrict__ outf)
{
  const int K = 1024;
  __shared__ __align__(16) unsigned short sAh[128*32];
  __shared__ __align__(16) unsigned short sBh[128*32];
  __shared__ __align__(16) unsigned short sAl[SPLIT ? 128*32 : 8];
  __shared__ __align__(16) unsigned short sBl[SPLIT ? 128*32 : 8];

  const int tid = threadIdx.x;
  const int lane = tid & 63;
  const int w = tid >> 6;
  const int wr = w >> 1, wc = w & 1;
  const int l16 = lane & 15, lg = lane >> 4;
  const int bm = blockIdx.x, bn = blockIdx.y;

  const int srow = (lane >> 2);
  const int scol = (lane & 3) * 8;
  const int r0 = w * 32;

  f32x4 acc[4][4];
  #pragma unroll
  for (int i = 0; i < 4; i++)
    #pragma unroll
    for (int j = 0; j < 4; j++)
      acc[i][j] = (f32x4){0.f,0.f,0.f,0.f};

  for (int kt = 0; kt < K/32; ++kt){
    __syncthreads();
    #pragma unroll
    for (int cc = 0; cc < 2; cc++){
      const int rr = r0 + cc*16 + srow;
      const int lb = (r0 + cc*16) * 32;
      gload16(&sAh[lb], &Ah[(size_t)(bm*128 + rr)*K + kt*32 + scol]);
      gload16(&sBh[lb], &Bh[(size_t)(bn*128 + rr)*K + kt*32 + scol]);
      if constexpr (SPLIT){
        gload16(&sAl[lb], &Al[(size_t)(bm*128 + rr)*K + kt*32 + scol]);
        gload16(&sBl[lb], &Bl[(size_t)(bn*128 + rr)*K + kt*32 + scol]);
      }
    }
    __syncthreads();

    bf16x8 afh[4], afl[4], bfh[4], bfl[4];
    #pragma unroll
    for (int mi = 0; mi < 4; mi++){
      int off = (wr*64 + mi*16 + l16)*32 + lg*8;
      afh[mi] = *(const bf16x8*)&sAh[off];
      if constexpr (SPLIT) afl[mi] = *(const bf16x8*)&sAl[off];
    }
    #pragma unroll
    for (int ni = 0; ni < 4; ni++){
      int off = (wc*64 + ni*16 + l16)*32 + lg*8;
      bfh[ni] = *(const bf16x8*)&sBh[off];
      if constexpr (SPLIT) bfl[ni] = *(const bf16x8*)&sBl[off];
    }
    #pragma unroll
    for (int mi = 0; mi < 4; mi++)
      #pragma unroll
      for (int ni = 0; ni < 4; ni++){
        acc[mi][ni] = __builtin_amdgcn_mfma_f32_16x16x32_bf16(afh[mi], bfh[ni], acc[mi][ni], 0, 0, 0);
        if constexpr (SPLIT){
          acc[mi][ni] = __builtin_amdgcn_mfma_f32_16x16x32_bf16(afh[mi], bfl[ni], acc[mi][ni], 0, 0, 0);
          acc[mi][ni] = __builtin_amdgcn_mfma_f32_16x16x32_bf16(afl[mi], bfh[ni], acc[mi][ni], 0, 0, 0);
        }
      }
  }

  if constexpr (EPI == 0){
    const int wsel = (bn * 128) >> 10;   // 0=Q,1=K,2=V
    const float* bias = (wsel == 0) ? bias0 : (wsel == 1) ? bias1 : bias2;
    #pragma unroll
    for (int mi = 0; mi < 4; mi++)
      #pragma unroll
      for (int ni = 0; ni < 4; ni++)
        #pragma unroll
        for (int i = 0; i < 4; i++){
          int m = bm*128 + wr*64 + mi*16 + lg*4 + i;
          int ng = bn*128 + wc*64 + ni*16 + l16;
          int n = ng & 1023;
          float v = acc[mi][ni][i] + bias[n];
          int b = m >> 11, s = m & 2047;
          int h = n >> 7, dh = n & 127;
          size_t base = (size_t)(b*8 + h)*262144;
          if (wsel == 2){
            size_t off = base + (size_t)(s>>5)*4096 + (dh>>4)*512
                       + (size_t)((((s>>3)&3)*16 + (dh&15))*8 + (s&7));
            vT[off] = f2bf(v);
          } else {
            size_t off = base + (size_t)(s>>4)*2048 + (dh>>5)*512
                       + (size_t)((((dh>>3)&3)*16 + (s&15))*8 + (dh&7));
            unsigned short hv = f2bf(v);
            if (wsel == 0){ qh[off] = hv; ql[off] = f2bf(v - bf2f(hv)); }
            else          { kh[off] = hv; kl[off] = f2bf(v - bf2f(hv)); }
          }
        }
  } else {
    #pragma unroll
    for (int mi = 0; mi < 4; mi++)
      #pragma unroll
      for (int ni = 0; ni < 4; ni++)
        #pragma unroll
        for (int i = 0; i < 4; i++){
          int m = bm*128 + wr*64 + mi*16 + lg*4 + i;
          int n = bn*128 + wc*64 + ni*16 + l16;
          outf[(size_t)m*1024 + n] = acc[mi][ni][i] + bias0[n];
        }
  }
}

// ---------------- fused attention v8 (R10/R11 version: 232 us, no fused tail) -----------------
__global__ __launch_bounds__(512, 4) void attn_kernel(
    const unsigned short* __restrict__ qh, const unsigned short* __restrict__ ql,
    const unsigned short* __restrict__ kh, const unsigned short* __restrict__ kl,
    const unsigned short* __restrict__ vT, float* __restrict__ attn_out)
{
  __shared__ __align__(16) float red[8][16][132];
  __shared__ float rpartm[8][16], rpartd[8][16];
  __shared__ unsigned int prefixv[16], kremv[16];
  unsigned int* hist = (unsigned int*)red;

  const int tid = threadIdx.x;
  const int lane = tid & 63;
  const int w = tid >> 6;
  const int l16 = lane & 15, lg = lane >> 4;
  const int swz = (blockIdx.x & 7) * 256 + (blockIdx.x >> 3);
  const int bh = swz >> 7, qb = swz & 127;
  const float scale = 0.08838834764831845f;

  const size_t base = (size_t)bh*262144;

  const size_t qpb = base + (size_t)qb*2048 + lane*8;
  bf16x8 aqh[4], aql[4];
  #pragma unroll
  for (int kk = 0; kk < 4; kk++){
    aqh[kk] = *(const bf16x8*)&qh[qpb + kk*512];
    aql[kk] = *(const bf16x8*)&ql[qpb + kk*512];
  }

  f32x4 acc[16];
  #pragma unroll
  for (int nt = 0; nt < 16; nt++){
    f32x4 a0 = (f32x4){0.f,0.f,0.f,0.f};
    f32x4 a1 = (f32x4){0.f,0.f,0.f,0.f};
    const size_t kb = base + (size_t)(w*16 + nt)*2048 + lane*8;
    __builtin_amdgcn_s_setprio(1);
    #pragma unroll
    for (int kk = 0; kk < 4; kk++){
      bf16x8 kbh = *(const bf16x8*)&kh[kb + kk*512];
      bf16x8 kbl = *(const bf16x8*)&kl[kb + kk*512];
      a0 = __builtin_amdgcn_mfma_f32_16x16x32_bf16(kbh, aqh[kk], a0, 0, 0, 0);
      a1 = __builtin_amdgcn_mfma_f32_16x16x32_bf16(kbh, aql[kk], a1, 0, 0, 0);
      a1 = __builtin_amdgcn_mfma_f32_16x16x32_bf16(kbl, aqh[kk], a1, 0, 0, 0);
    }
    __builtin_amdgcn_s_setprio(0);
    #pragma unroll
    for (int i = 0; i < 4; i++) acc[nt][i] = (a0[i] + a1[i]) * scale;
  }

  {
    float rm = -3.4e38f;
    #pragma unroll
    for (int nt = 0; nt < 16; nt++)
      #pragma unroll
      for (int i = 0; i < 4; i++) rm = fmaxf(rm, acc[nt][i]);
    rm = fmaxf(rm, __shfl_xor(rm, 16, 64));
    rm = fmaxf(rm, __shfl_xor(rm, 32, 64));
    if (lane < 16) rpartm[w][lane] = rm;
  }
  if (tid < 16){ prefixv[tid] = 0u; kremv[tid] = 204u; }

  #pragma unroll
  for (int nt = 0; nt < 16; nt++)
    #pragma unroll
    for (int i = 0; i < 4; i++)
      acc[nt][i] = __uint_as_float(fkey(acc[nt][i]));

  const int hco = (w >> 1) * (16*257);
  for (int pass = 3; pass >= 0; pass--){
    const int shift = pass*8;
    __syncthreads();
    for (int j = tid; j < 4*16*257; j += 512) hist[j] = 0u;
    __syncthreads();
    const unsigned int pf = prefixv[l16];
    const unsigned int mhi = (pass == 3) ? 0u : (0xFFFFFFFFu << (shift + 8));
    #pragma unroll
    for (int nt = 0; nt < 16; nt++)
      #pragma unroll
      for (int i = 0; i < 4; i++){
        unsigned int u = __float_as_uint(acc[nt][i]);
        if ((u & mhi) == pf)
          atomicAdd(&hist[hco + l16*257 + ((u >> shift) & 255u)], 1u);
      }
    __syncthreads();
    #pragma unroll
    for (int rr = 0; rr < 2; rr++){
      int r = w*2 + rr;
      unsigned int krem = kremv[r];
      unsigned int pfx  = prefixv[r];
      unsigned int cl[4], s4 = 0;
      #pragma unroll
      for (int t = 0; t < 4; t++){
        int idx = r*257 + 255 - 4*lane - t;
        cl[t] = hist[idx] + hist[16*257 + idx] + hist[2*16*257 + idx] + hist[3*16*257 + idx];
        s4 += cl[t];
      }
      unsigned int inc = s4;
      #pragma unroll
      for (int off = 1; off < 64; off <<= 1){
        unsigned int v = __shfl_up((int)inc, off, 64);
        if (lane >= off) inc += v;
      }
      unsigned int cb = inc - s4;
      #pragma unroll
      for (int t = 0; t < 4; t++){
        if (krem > cb && krem <= cb + cl[t]){
          int d = 255 - 4*lane - t;
          prefixv[r] = pfx | ((unsigned int)d << shift);
          kremv[r]   = krem - cb;
        }
        cb += cl[t];
      }
    }
  }
  __syncthreads();

  const unsigned int th = prefixv[l16];
  float rmax = rpartm[0][l16];
  #pragma unroll
  for (int w8 = 1; w8 < 8; w8++) rmax = fmaxf(rmax, rpartm[w8][l16]);
  const int src01 = ((lg & 1) << 5) + l16;
  const int src23 = src01 + 16;
  const size_t vb0 = base + (size_t)(w*8)*4096 + lane*8;
  float dn = 0.f;
  f32x4 pacc[8];
  #pragma unroll
  for (int dt = 0; dt < 8; dt++) pacc[dt] = (f32x4){0.f,0.f,0.f,0.f};
  #pragma unroll
  for (int t = 0; t < 8; t++){
    float p[8];
    #pragma unroll
    for (int j = 0; j < 4; j++){
      unsigned int u = __float_as_uint(acc[2*t][j]);
      p[j] = (u >= th) ? __expf(fkeyinv(u) - rmax) : 0.f;
    }
    #pragma unroll
    for (int j = 0; j < 4; j++){
      unsigned int u = __float_as_uint(acc[2*t+1][j]);
      p[4+j] = (u >= th) ? __expf(fkeyinv(u) - rmax) : 0.f;
    }
    unsigned int d0 = cvtpk(p[0], p[1]), d1 = cvtpk(p[2], p[3]);
    unsigned int d2 = cvtpk(p[4], p[5]), d3 = cvtpk(p[6], p[7]);
    dn += __uint_as_float(d0 << 16) + __uint_as_float(d0 & 0xFFFF0000u)
        + __uint_as_float(d1 << 16) + __uint_as_float(d1 & 0xFFFF0000u)
        + __uint_as_float(d2 << 16) + __uint_as_float(d2 & 0xFFFF0000u)
        + __uint_as_float(d3 << 16) + __uint_as_float(d3 & 0xFFFF0000u);
    unsigned int A0 = (unsigned int)__shfl((int)d0, src01, 64);
    unsigned int A1 = (unsigned int)__shfl((int)d1, src01, 64);
    unsigned int A2 = (unsigned int)__shfl((int)d0, src23, 64);
    unsigned int A3 = (unsigned int)__shfl((int)d1, src23, 64);
    unsigned int B0 = (unsigned int)__shfl((int)d2, src01, 64);
    unsigned int B1 = (unsigned int)__shfl((int)d3, src01, 64);
    unsigned int B2 = (unsigned int)__shfl((int)d2, src23, 64);
    unsigned int B3 = (unsigned int)__shfl((int)d3, src23, 64);
    u32x4 pdv = (lg < 2) ? (u32x4){A0, A1, A2, A3} : (u32x4){B0, B1, B2, B3};
    bf16x8 pa = __builtin_bit_cast(bf16x8, pdv);
    __builtin_amdgcn_s_setprio(1);
    #pragma unroll
    for (int dt = 0; dt < 8; dt++){
      bf16x8 bv = *(const bf16x8*)&vT[vb0 + (size_t)t*4096 + dt*512];
      pacc[dt] = __builtin_amdgcn_mfma_f32_16x16x32_bf16(pa, bv, pacc[dt], 0, 0, 0);
    }
    __builtin_amdgcn_s_setprio(0);
  }
  dn += __shfl_xor(dn, 16, 64);
  dn += __shfl_xor(dn, 32, 64);
  if (lane < 16) rpartd[w][lane] = dn;

  #pragma unroll
  for (int dt = 0; dt < 8; dt++)
    #pragma unroll
    for (int i = 0; i < 4; i++)
      red[w][lg*4 + i][dt*16 + l16] = pacc[dt][i];
  __syncthreads();

  {
    const int q = tid >> 5;
    const int c0 = (tid & 31) * 4;
    f32x4 s0 = (f32x4){0.f,0.f,0.f,0.f};
    #pragma unroll
    for (int w8 = 0; w8 < 8; w8++)
      s0 += *(const f32x4*)&red[w8][q][c0];
    float dnm = 0.f;
    #pragma unroll
    for (int w8 = 0; w8 < 8; w8++) dnm += rpartd[w8][q];
    const int b = bh >> 3, h = bh & 7;
    float* op = &attn_out[((size_t)b*2048 + qb*16 + q)*1024 + h*128 + c0];
    f32x4 o0;
    #pragma unroll
    for (int i = 0; i < 4; i++) o0[i] = s0[i] / dnm;
    *(f32x4*)op = o0;
  }
}

// ---------------- mean over S: 256 blocks of 16-row partial sums ----------------
__global__ void mean_partial_kernel(const float* __restrict__ x, float* __restrict__ partial){
  int b = blockIdx.x >> 7, ch = blockIdx.x & 127;
  int tid = threadIdx.x;
  #pragma unroll
  for (int dc = 0; dc < 4; dc++){
    int d = dc*256 + tid;
    float s = 0.f;
    for (int ss = 0; ss < 16; ss++) s += x[((size_t)b*2048 + ch*16 + ss)*1024 + d];
    partial[((size_t)b*128 + ch)*1024 + d] = s;
  }
}

// ---------------- gate (merged): xmean -> sigmoid dots -> Wgp projection ----------------------
__global__ __launch_bounds__(512) void gate_kernel2(const float* __restrict__ partial,
    const float* __restrict__ Wg, const float* __restrict__ bg,
    const float* __restrict__ Wgp, const float* __restrict__ bgp, float* __restrict__ gate){
  __shared__ float xm[1024];
  __shared__ float gb[64];
  const int b = blockIdx.x;
  const int tid = threadIdx.x, lane = tid & 63, w = tid >> 6;
  for (int d = tid; d < 1024; d += 512){
    float s = 0.f;
    for (int c = 0; c < 128; c++) s += partial[((size_t)b*128 + c)*1024 + d];
    xm[d] = s * (1.f/2048.f);
  }
  __syncthreads();
  for (int jj = 0; jj < 8; jj++){
    const int j = w*8 + jj;
    float s = 0.f;
    #pragma unroll
    for (int c = 0; c < 4; c++){
      f32x4 wv = *(const f32x4*)&Wg[(size_t)j*1024 + lane*16 + c*4];
      s += wv[0]*xm[lane*16 + c*4] + wv[1]*xm[lane*16 + c*4 + 1]
         + wv[2]*xm[lane*16 + c*4 + 2] + wv[3]*xm[lane*16 + c*4 + 3];
    }
    #pragma unroll
    for (int off = 1; off < 64; off <<= 1) s += __shfl_xor(s, off, 64);
    if (lane == 0) gb[j] = 1.f / (1.f + __expf(-(s + bg[j])));
  }
  __syncthreads();
  for (int d = tid; d < 1024; d += 512){
    float s = bgp[d];
    #pragma unroll
    for (int j4 = 0; j4 < 16; j4++){
      f32x4 wv = *(const f32x4*)&Wgp[(size_t)d*64 + j4*4];
      s += wv[0]*gb[j4*4] + wv[1]*gb[j4*4+1] + wv[2]*gb[j4*4+2] + wv[3]*gb[j4*4+3];
    }
    gate[b*1024 + d] = s;
  }
}

// ---------------- distill + mix, write mixed as split bf16 (hi+lo) ----------------
__global__ __launch_bounds__(256) void mix_kernel(const float* __restrict__ attn,
    const float* __restrict__ Wd, const float* __restrict__ bd,
    const float* __restrict__ gate,
    unsigned short* __restrict__ mixedh, unsigned short* __restrict__ mixedl){
  __shared__ float sWdT[64*64];
  __shared__ float arow[1024];
  int tid = threadIdx.x;
  for (int i = tid; i < 4096; i += 256){
    int m = i >> 6, cc = i & 63;
    sWdT[i] = Wd[cc*64 + m];
  }
  int rbase = blockIdx.x * 16;
  for (int rr = 0; rr < 16; rr++){
    int row = rbase + rr;
    __syncthreads();
    for (int i = tid; i < 1024; i += 256) arow[i] = attn[(size_t)row*1024 + i];
    __syncthreads();
    int b = row >> 11;
    #pragma unroll
    for (int c4 = 0; c4 < 4; c4++){
      int dcol = c4*256 + tid;
      int j = dcol >> 6, cc = dcol & 63;
      float y = bd[cc];
      for (int m = 0; m < 64; m++) y += arow[j*64 + m] * sWdT[m*64 + cc];
      float g = gate[b*1024 + dcol];
      float mv = g*y + (1.f - g)*arow[dcol];
      unsigned short hv = f2bf(mv);
      mixedh[(size_t)row*1024 + dcol] = hv;
      mixedl[(size_t)row*1024 + dcol] = f2bf(mv - bf2f(hv));
    }
  }
}

// ---------------- launch ----------------
// Workspace layout (total 68 MiB; replay-proven safe):
//   [ 0, 8)  MiB xh      (dead after QKV gemm)   } attnws [0,16) aliases both
//   [ 8,16)  MiB xl      (dead after QKV gemm)   }
//   [16,22)  MiB whi     (dead after QKV gemm)   } wohi [16,18), wolo [18,20),
//   [22,28)  MiB wlo     (dead after QKV gemm)   } partial [20,21), gatews [21,+8K)
//   [28,36)  MiB qh (packed) -> mixedh after attn
//   [36,44)  MiB ql (packed) -> mixedl after attn
//   [44,52)  MiB kh (packed)   [52,60) kl (packed)   [60,68) vT (packed)
extern "C" void kernel_launch(void* const* d_in, const int* in_sizes, int n_in,
                              void* d_out, int out_size, void* d_ws, size_t ws_size,
                              hipStream_t stream){
  (void)in_sizes; (void)n_in; (void)out_size; (void)ws_size;
  const float* x   = (const float*)d_in[0];
  const float* Wq  = (const float*)d_in[1];
  const float* bq  = (const float*)d_in[2];
  const float* Wk  = (const float*)d_in[3];
  const float* bk  = (const float*)d_in[4];
  const float* Wv  = (const float*)d_in[5];
  const float* bv  = (const float*)d_in[6];
  const float* Wo  = (const float*)d_in[7];
  const float* bo  = (const float*)d_in[8];
  const float* Wd  = (const float*)d_in[9];
  const float* bd  = (const float*)d_in[10];
  const float* Wg  = (const float*)d_in[11];
  const float* bg  = (const float*)d_in[12];
  const float* Wgp = (const float*)d_in[13];
  const float* bgp = (const float*)d_in[14];
  float* out = (float*)d_out;

  const size_t MiB = 1048576;
  char* ws = (char*)d_ws;
  unsigned short* xh     = (unsigned short*)(ws + 0*MiB);
  unsigned short* xl     = (unsigned short*)(ws + 8*MiB);
  float*          attnws = (float*)(ws + 0*MiB);            // aliases xh/xl after QKV
  unsigned short* whi    = (unsigned short*)(ws + 16*MiB);  // [3072,1024]
  unsigned short* wlo    = (unsigned short*)(ws + 22*MiB);
  unsigned short* wohi   = (unsigned short*)(ws + 16*MiB);  // aliases whi, written after QKV
  unsigned short* wolo   = (unsigned short*)(ws + 18*MiB);
  float*          partial= (float*)(ws + 20*MiB);           // 1 MiB
  float*          gatews = (float*)(ws + 21*MiB);           // 8 KiB
  unsigned short* qh_    = (unsigned short*)(ws + 28*MiB);
  unsigned short* ql_    = (unsigned short*)(ws + 36*MiB);
  unsigned short* mixedh = (unsigned short*)(ws + 28*MiB);  // aliases qh after attn
  unsigned short* mixedl = (unsigned short*)(ws + 36*MiB);  // aliases ql after attn
  unsigned short* kh_    = (unsigned short*)(ws + 44*MiB);
  unsigned short* kl_    = (unsigned short*)(ws + 52*MiB);
  unsigned short* vT_    = (unsigned short*)(ws + 60*MiB);  // ends at 68 MiB

  prep_all_kernel<<<28672, 256, 0, stream>>>(x, Wq, Wk, Wv, xh, xl, whi, wlo);

  gemm_kernel<true, 0><<<dim3(32, 24), 256, 0, stream>>>(
      xh, xl, whi, wlo, bq, bk, bv, qh_, ql_, kh_, kl_, vT_, nullptr);

  prep_split_kernel<<<4096, 256, 0, stream>>>(Wo, wohi, wolo, 1048576);
  mean_partial_kernel<<<256, 256, 0, stream>>>(x, partial);
  gate_kernel2<<<2, 512, 0, stream>>>(partial, Wg, bg, Wgp, bgp, gatews);

  attn_kernel<<<2048, 512, 0, stream>>>(qh_, ql_, kh_, kl_, vT_, attnws);

  mix_kernel<<<256, 256, 0, stream>>>(attnws, Wd, bd, gatews, mixedh, mixedl);

  gemm_kernel<true, 1><<<dim3(32, 8), 256, 0, stream>>>(
      mixedh, mixedl, wohi, wolo, bo, nullptr, nullptr,
      nullptr, nullptr, nullptr, nullptr, nullptr, out);
}